// Round 7
// baseline (236.928 us; speedup 1.0000x reference)
//
#include <hip/hip_runtime.h>
#include <stdint.h>
#include <stddef.h>

// ---------------------------------------------------------------------------
// SelfAttention: out = softmax((x W1^T + b1)(x W2^T + b2)^T) (x W2^T + b2)
// B=4, L=2048, D=1024. fp32 in/out; fp16 MFMA internals.
// Round 16: r14/r15 never ran (two container infra failures) — resubmitting
// unchanged: r12-proven 2-barrier GEMMs + T1 XCD-aware block swizzle on
// proj/score/out (all grids %8==0 -> simple bijective remap). Consecutive
// dispatch ids round-robin the 8 XCDs; remap gives each XCD a contiguous
// x-fastest tile run -> B-panel (W / V / Vt) reuse lands in that XCD's
// private L2. XOR k-chunk swizzle everywhere (r3: conflicts 4.2e6 -> 0).
// ---------------------------------------------------------------------------

typedef _Float16  f16_t;
typedef _Float16  f16x8 __attribute__((ext_vector_type(8)));
typedef float     f32x4 __attribute__((ext_vector_type(4)));

__device__ __forceinline__ f32x4 mfma16(f16x8 a, f16x8 b, f32x4 c) {
  return __builtin_amdgcn_mfma_f32_16x16x32_f16(a, b, c, 0, 0, 0);
}

__device__ __forceinline__ void async_copy16(const f16_t* g, f16_t* l) {
  __builtin_amdgcn_global_load_lds(
      (const __attribute__((address_space(1))) unsigned int*)(g),
      (__attribute__((address_space(3))) unsigned int*)(l),
      16, 0, 0);
}

// T1: bijective XCD chunking remap (requires nwg % 8 == 0).
__device__ __forceinline__ int xcd_swz(int lid, int nwg) {
  return (lid & 7) * (nwg >> 3) + (lid >> 3);
}

// C = A * B^T on a (RM*32) x (RN*32) tile, K = nk*NS*32, K contiguous.
// 4 waves 2x2; wave quadrant (RM*16) x (RN*16). Per iter: stage NS 32-k
// slices, one barrier pair, NS*RM*RN MFMAs per wave. k-chunks XOR-swizzled.
template <int RM, int RN, int NS>
__device__ __forceinline__ void gemm_core(
    const f16_t* __restrict__ A, const f16_t* __restrict__ B,
    int lda, int ldb, int nk,
    f16_t* __restrict__ As, f16_t* __restrict__ Bs, f32x4 (&acc)[RM][RN])
{
  const int tid  = threadIdx.x;
  const int lane = tid & 63;
  const int w    = tid >> 6;
  const int wr   = (w >> 1) * (RM * 16);
  const int wc   = (w & 1) * (RN * 16);
  const int l16  = lane & 15;
  const int quad = lane >> 4;
  const int sw   = (quad ^ ((l16 >> 1) & 3)) * 8;

  const int r0  = tid >> 2;
  const int kc0 = ((tid & 3) ^ ((r0 >> 1) & 3)) * 8;

  const f16_t* Ag = A + (size_t)r0 * lda + kc0;
  const f16_t* Bg = B + (size_t)r0 * ldb + kc0;

  for (int kt = 0; kt < nk; ++kt) {
#pragma unroll
    for (int s = 0; s < NS; ++s) {
      const int ko = s * 32;
#pragma unroll
      for (int h = 0; h < RM / 2; ++h)
        async_copy16(Ag + ko + (size_t)(64 * h) * lda,
                     As + s * RM * 1024 + (tid + 256 * h) * 8);
#pragma unroll
      for (int h = 0; h < RN / 2; ++h)
        async_copy16(Bg + ko + (size_t)(64 * h) * ldb,
                     Bs + s * RN * 1024 + (tid + 256 * h) * 8);
    }
    __syncthreads();

#pragma unroll
    for (int s = 0; s < NS; ++s) {
      const f16_t* Ac = As + s * RM * 1024;
      const f16_t* Bc = Bs + s * RN * 1024;
      f16x8 af[RM], bf[RN];
#pragma unroll
      for (int i = 0; i < RM; ++i)
        af[i] = *(const f16x8*)(Ac + (wr + i * 16 + l16) * 32 + sw);
#pragma unroll
      for (int j = 0; j < RN; ++j)
        bf[j] = *(const f16x8*)(Bc + (wc + j * 16 + l16) * 32 + sw);
#pragma unroll
      for (int i = 0; i < RM; ++i)
#pragma unroll
        for (int j = 0; j < RN; ++j)
          acc[i][j] = mfma16(af[i], bf[j], acc[i][j]);
    }

    __syncthreads();
    Ag += NS * 32; Bg += NS * 32;
  }
}

// ---------------------------------------------------------------------------
// 0) fp32 -> fp16 for x, W1, W2 in one launch. Grid 5120 x 256 x 8 elems.
__global__ __launch_bounds__(256) void cvt_kernel(
    const float* __restrict__ x, const float* __restrict__ W1,
    const float* __restrict__ W2, f16_t* __restrict__ xh,
    f16_t* __restrict__ W1h, f16_t* __restrict__ W2h)
{
  const size_t XN = (size_t)8192 * 1024;
  const size_t WN = (size_t)1024 * 1024;
  size_t i = ((size_t)blockIdx.x * 256 + threadIdx.x) * 8;
  const float* in; f16_t* out;
  if (i < XN)            { in = x;  out = xh; }
  else if (i < XN + WN)  { in = W1; out = W1h; i -= XN; }
  else                   { in = W2; out = W2h; i -= XN + WN; }
  f32x4 a = *(const f32x4*)(in + i);
  f32x4 b = *(const f32x4*)(in + i + 4);
  f16x8 o;
#pragma unroll
  for (int k = 0; k < 4; ++k) { o[k] = (f16_t)a[k]; o[k + 4] = (f16_t)b[k]; }
  *(f16x8*)(out + i) = o;
}

// ---------------------------------------------------------------------------
// 1) fused projection, 128x64 tiles (RM=4, RN=2), BK=64 (r12):
//    Q = xW1^T+b1, V = xW2^T+b2, Vt via pitch-136 LDS transpose epilogue.
//    Grid 1024 linear, T1-swizzled onto (64 x 16) tiles (4 blocks/CU).
__global__ __launch_bounds__(256) void proj_qv_kernel(
    const f16_t* __restrict__ X, const f16_t* __restrict__ W1,
    const f16_t* __restrict__ W2, const float* __restrict__ b1,
    const float* __restrict__ b2, f16_t* __restrict__ Q,
    f16_t* __restrict__ V, f16_t* __restrict__ Vt)
{
  __shared__ __align__(16) f16_t smem[16384];   // 32 KB arena
  f16_t* Xs  = smem;                            // 2 x 128x32 = 8192 f16
  f16_t* W1s = smem + 8192;                     // 2 x  64x32 = 4096 f16
  f16_t* W2s = smem + 12288;                    // 2 x  64x32 = 4096 f16
  constexpr int XSZ = 128 * 32;
  constexpr int WSZ = 64 * 32;

  const int tile = xcd_swz(blockIdx.x, 1024);   // T1
  const int m0 = (tile & 63) * 128;             // x-fastest: row tile
  const int n0 = (tile >> 6) * 64;              // col tile (W-panel shared)

  const int tid  = threadIdx.x;
  const int lane = tid & 63;
  const int w    = tid >> 6;
  const int wr   = (w >> 1) * 64;
  const int wc   = (w & 1) * 32;
  const int quad = lane >> 4;
  const int l16  = lane & 15;
  const int sw   = (quad ^ ((l16 >> 1) & 3)) * 8;
  const int r0   = tid >> 2;
  const int kc0  = ((tid & 3) ^ ((r0 >> 1) & 3)) * 8;

  const f16_t* Xg = X + (size_t)(m0 + r0) * 1024 + kc0;
  const f16_t* G1 = W1 + (size_t)(n0 + r0) * 1024 + kc0;
  const f16_t* G2 = W2 + (size_t)(n0 + r0) * 1024 + kc0;

  f32x4 accQ[4][2] = {};
  f32x4 accV[4][2] = {};

  for (int kt = 0; kt < 16; ++kt) {
#pragma unroll
    for (int s = 0; s < 2; ++s) {
      const int ko = s * 32;
      async_copy16(Xg + ko, Xs + s * XSZ + tid * 8);
      async_copy16(Xg + ko + (size_t)64 * 1024, Xs + s * XSZ + (tid + 256) * 8);
      async_copy16(G1 + ko, W1s + s * WSZ + tid * 8);
      async_copy16(G2 + ko, W2s + s * WSZ + tid * 8);
    }
    __syncthreads();

#pragma unroll
    for (int s = 0; s < 2; ++s) {
      f16x8 xf[4], w1f[2], w2f[2];
#pragma unroll
      for (int i = 0; i < 4; ++i)
        xf[i]  = *(const f16x8*)(Xs  + s * XSZ + (wr + i * 16 + l16) * 32 + sw);
#pragma unroll
      for (int j = 0; j < 2; ++j) {
        w1f[j] = *(const f16x8*)(W1s + s * WSZ + (wc + j * 16 + l16) * 32 + sw);
        w2f[j] = *(const f16x8*)(W2s + s * WSZ + (wc + j * 16 + l16) * 32 + sw);
      }
#pragma unroll
      for (int i = 0; i < 4; ++i)
#pragma unroll
        for (int j = 0; j < 2; ++j) {
          accQ[i][j] = mfma16(xf[i], w1f[j], accQ[i][j]);
          accV[i][j] = mfma16(xf[i], w2f[j], accV[i][j]);
        }
    }
    __syncthreads();
    Xg += 64; G1 += 64; G2 += 64;
  }

  f16_t* Ts = smem;
#pragma unroll
  for (int j = 0; j < 2; ++j) {
    const int c   = wc + j * 16 + l16;
    const int col = n0 + c;
    const float bq = b1[col], bv = b2[col];
#pragma unroll
    for (int i = 0; i < 4; ++i)
#pragma unroll
      for (int r = 0; r < 4; ++r) {
        const int k   = wr + i * 16 + quad * 4 + r;
        const int row = m0 + k;
        const float q = accQ[i][j][r] + bq;
        const float v = accV[i][j][r] + bv;
        Q[(size_t)row * 1024 + col] = (f16_t)q;
        V[(size_t)row * 1024 + col] = (f16_t)v;
        Ts[c * 136 + k] = (f16_t)v;
      }
  }
  __syncthreads();

  const size_t vtbase = ((size_t)(m0 >> 11) << 21) + (size_t)n0 * 2048 + (m0 & 2047);
#pragma unroll
  for (int rep = 0; rep < 4; ++rep) {
    const int d  = rep * 16 + (tid >> 4);
    const int c4 = tid & 15;
    f16x8 vv = *(const f16x8*)(Ts + d * 136 + c4 * 8);
    *(f16x8*)(Vt + vtbase + (size_t)d * 2048 + c4 * 8) = vv;
  }
}

// ---------------------------------------------------------------------------
// 2) scores: S[b][q][k] = Q[b,q,:] . V[b,k,:], written FP16. 128x128 tile,
//    BK=64, LDS 32 KB, grid 1024 linear T1-swizzled onto (16,16,4)
//    (4 blocks/CU), 16 barrier pairs.
__global__ __launch_bounds__(256) void score_kernel(
    const f16_t* __restrict__ Q, const f16_t* __restrict__ V,
    f16_t* __restrict__ S)
{
  __shared__ __align__(16) f16_t As[2 * 128 * 32];   // 16 KB
  __shared__ __align__(16) f16_t Bs[2 * 128 * 32];   // 16 KB

  const int lid  = blockIdx.x + 16 * (blockIdx.y + 16 * blockIdx.z);
  const int tile = xcd_swz(lid, 1024);               // T1
  const int m0 = (tile & 15) * 128;                  // x-fastest: row tile
  const int n0 = ((tile >> 4) & 15) * 128;           // V-panel shared in XCD
  const int bz = tile >> 8;
  const size_t boff = (size_t)bz * 2048 * 1024;

  f32x4 acc[4][4] = {};
  gemm_core<4, 4, 2>(Q + boff + (size_t)m0 * 1024,
                     V + boff + (size_t)n0 * 1024,
                     1024, 1024, 1024 / 64, As, Bs, acc);

  f16_t* Sb = S + (size_t)bz * 2048 * 2048;
  const int lane = threadIdx.x & 63;
  const int w    = threadIdx.x >> 6;
  const int wr   = (w >> 1) * 64, wc = (w & 1) * 64;
  const int quad = lane >> 4,     l16 = lane & 15;

#pragma unroll
  for (int i = 0; i < 4; ++i)
#pragma unroll
    for (int j = 0; j < 4; ++j)
#pragma unroll
      for (int r = 0; r < 4; ++r) {
        const int row = m0 + wr + i * 16 + quad * 4 + r;
        const int col = n0 + wc + j * 16 + l16;
        Sb[(size_t)row * 2048 + col] = (f16_t)acc[i][j][r];
      }
}

// ---------------------------------------------------------------------------
// 3) softmax over each 2048-f16 row of S; fp16 P in-place. Each thread owns
//    its 8 elements; exp/max/sum in fp32.
__global__ __launch_bounds__(256) void softmax_kernel(f16_t* __restrict__ S)
{
  f16_t* row = S + (size_t)blockIdx.x * 2048;
  const int tid  = threadIdx.x;
  const int lane = tid & 63;
  const int w    = tid >> 6;

  f16x8 v = *((const f16x8*)row + tid);
  float f[8];
#pragma unroll
  for (int k = 0; k < 8; ++k) f[k] = (float)v[k];

  float m = f[0];
#pragma unroll
  for (int k = 1; k < 8; ++k) m = fmaxf(m, f[k]);
#pragma unroll
  for (int off = 32; off >= 1; off >>= 1) m = fmaxf(m, __shfl_xor(m, off));

  __shared__ float red[4];
  if (lane == 0) red[w] = m;
  __syncthreads();
  m = fmaxf(fmaxf(red[0], red[1]), fmaxf(red[2], red[3]));

  float s = 0.f;
#pragma unroll
  for (int k = 0; k < 8; ++k) { f[k] = __expf(f[k] - m); s += f[k]; }
#pragma unroll
  for (int off = 32; off >= 1; off >>= 1) s += __shfl_xor(s, off);
  __syncthreads();
  if (lane == 0) red[w] = s;
  __syncthreads();
  s = (red[0] + red[1]) + (red[2] + red[3]);
  const float inv = 1.f / s;

  f16x8 o;
#pragma unroll
  for (int k = 0; k < 8; ++k) o[k] = (f16_t)(f[k] * inv);
  *((f16x8*)row + tid) = o;
}

// ---------------------------------------------------------------------------
// 4) out[b][q][d] = sum_k P[b][q][k] * Vt[b][d][k] -> fp32. P pitch 2048 f16.
//    128x128 tile, BK=64, LDS 32 KB, grid 512 linear T1-swizzled onto
//    (16,8,4) (2 blocks/CU).
__global__ __launch_bounds__(256) void out_kernel(
    const f16_t* __restrict__ P, const f16_t* __restrict__ Vt,
    float* __restrict__ Out)
{
  __shared__ __align__(16) f16_t As[2 * 128 * 32];   // 16 KB
  __shared__ __align__(16) f16_t Bs[2 * 128 * 32];   // 16 KB

  const int lid  = blockIdx.x + 16 * (blockIdx.y + 8 * blockIdx.z);
  const int tile = xcd_swz(lid, 512);                // T1
  const int m0 = (tile & 15) * 128;                  // x-fastest: row tile
  const int n0 = ((tile >> 4) & 7) * 128;            // Vt-panel shared in XCD
  const int bz = tile >> 7;
  const size_t poff  = (size_t)bz * 2048 * 2048;
  const size_t vtoff = (size_t)bz * 1024 * 2048;

  f32x4 acc[4][4] = {};
  gemm_core<4, 4, 2>(P + poff + (size_t)m0 * 2048,
                     Vt + vtoff + (size_t)n0 * 2048,
                     2048, 2048, 2048 / 64, As, Bs, acc);

  float* Ob = Out + (size_t)bz * 2048 * 1024;
  const int lane = threadIdx.x & 63;
  const int w    = threadIdx.x >> 6;
  const int wr   = (w >> 1) * 64, wc = (w & 1) * 64;
  const int quad = lane >> 4,     l16 = lane & 15;

#pragma unroll
  for (int i = 0; i < 4; ++i)
#pragma unroll
    for (int j = 0; j < 4; ++j)
#pragma unroll
      for (int r = 0; r < 4; ++r) {
        const int row = m0 + wr + i * 16 + quad * 4 + r;
        const int col = n0 + wc + j * 16 + l16;
        Ob[(size_t)row * 1024 + col] = acc[i][j][r];
      }
}

// ---------------------------------------------------------------------------
extern "C" void kernel_launch(void* const* d_in, const int* in_sizes, int n_in,
                              void* d_out, int out_size, void* d_ws, size_t ws_size,
                              hipStream_t stream) {
  const float* x  = (const float*)d_in[0];
  const float* W1 = (const float*)d_in[1];
  const float* b1 = (const float*)d_in[2];
  const float* W2 = (const float*)d_in[3];
  const float* b2 = (const float*)d_in[4];
  float* out = (float*)d_out;

  const size_t QN = (size_t)8192 * 1024;
  const size_t WN = (size_t)1024 * 1024;
  f16_t* xh  = (f16_t*)d_ws;       // 16 MiB
  f16_t* W1h = xh + QN;            //  2 MiB
  f16_t* W2h = W1h + WN;           //  2 MiB
  f16_t* Q   = W2h + WN;           // 16 MiB
  f16_t* V   = Q + QN;             // 16 MiB
  f16_t* Vt  = V + QN;             // 16 MiB [4][1024][2048]
  f16_t* S   = Vt + QN;            // 32 MiB fp16 [4][2048][2048], P in-place

  dim3 blk(256);
  cvt_kernel<<<5120, blk, 0, stream>>>(x, W1, W2, xh, W1h, W2h);
  proj_qv_kernel<<<1024, blk, 0, stream>>>(xh, W1h, W2h, b1, b2, Q, V, Vt);
  score_kernel<<<dim3(16, 16, 4), blk, 0, stream>>>(Q, V, S);
  softmax_kernel<<<8192, blk, 0, stream>>>(S);
  out_kernel<<<dim3(16, 8, 4), blk, 0, stream>>>(S, Vt, out);
}

// Round 8
// 225.606 us; speedup vs baseline: 1.0502x; 1.0502x over previous
//
#include <hip/hip_runtime.h>
#include <stdint.h>
#include <stddef.h>

// ---------------------------------------------------------------------------
// SelfAttention: out = softmax((x W1^T + b1)(x W2^T + b2)^T) (x W2^T + b2)
// B=4, L=2048, D=1024. fp32 in/out; fp16 MFMA internals.
// Round 17: T1 XCD swizzle REFUTED on this problem (r16: proj FETCH 32.8->133
// MB, +6.5 µs; default dispatch order was already cache-optimal; score/out
// neutral). REVERTED to r12-exact GEMMs (measured 229.6 µs).
// New: softmax reworked to one row per HALF-WAVE (8 rows/block, 1024 blocks):
// no LDS, no __syncthreads, shfl_xor(16..1) reductions stay within the
// 32-lane half; two passes over 8 f16x8 chunks held in regs (max, then
// exp/sum/normalize). Same coalescing (512B per chunk per half-wave).
// XOR k-chunk swizzle in GEMMs (r3: conflicts 4.2e6 -> 0).
// ---------------------------------------------------------------------------

typedef _Float16  f16_t;
typedef _Float16  f16x8 __attribute__((ext_vector_type(8)));
typedef float     f32x4 __attribute__((ext_vector_type(4)));

__device__ __forceinline__ f32x4 mfma16(f16x8 a, f16x8 b, f32x4 c) {
  return __builtin_amdgcn_mfma_f32_16x16x32_f16(a, b, c, 0, 0, 0);
}

__device__ __forceinline__ void async_copy16(const f16_t* g, f16_t* l) {
  __builtin_amdgcn_global_load_lds(
      (const __attribute__((address_space(1))) unsigned int*)(g),
      (__attribute__((address_space(3))) unsigned int*)(l),
      16, 0, 0);
}

// C = A * B^T on a (RM*32) x (RN*32) tile, K = nk*NS*32, K contiguous.
// 4 waves 2x2; wave quadrant (RM*16) x (RN*16). Per iter: stage NS 32-k
// slices, one barrier pair, NS*RM*RN MFMAs per wave. k-chunks XOR-swizzled.
template <int RM, int RN, int NS>
__device__ __forceinline__ void gemm_core(
    const f16_t* __restrict__ A, const f16_t* __restrict__ B,
    int lda, int ldb, int nk,
    f16_t* __restrict__ As, f16_t* __restrict__ Bs, f32x4 (&acc)[RM][RN])
{
  const int tid  = threadIdx.x;
  const int lane = tid & 63;
  const int w    = tid >> 6;
  const int wr   = (w >> 1) * (RM * 16);
  const int wc   = (w & 1) * (RN * 16);
  const int l16  = lane & 15;
  const int quad = lane >> 4;
  const int sw   = (quad ^ ((l16 >> 1) & 3)) * 8;

  const int r0  = tid >> 2;
  const int kc0 = ((tid & 3) ^ ((r0 >> 1) & 3)) * 8;

  const f16_t* Ag = A + (size_t)r0 * lda + kc0;
  const f16_t* Bg = B + (size_t)r0 * ldb + kc0;

  for (int kt = 0; kt < nk; ++kt) {
#pragma unroll
    for (int s = 0; s < NS; ++s) {
      const int ko = s * 32;
#pragma unroll
      for (int h = 0; h < RM / 2; ++h)
        async_copy16(Ag + ko + (size_t)(64 * h) * lda,
                     As + s * RM * 1024 + (tid + 256 * h) * 8);
#pragma unroll
      for (int h = 0; h < RN / 2; ++h)
        async_copy16(Bg + ko + (size_t)(64 * h) * ldb,
                     Bs + s * RN * 1024 + (tid + 256 * h) * 8);
    }
    __syncthreads();

#pragma unroll
    for (int s = 0; s < NS; ++s) {
      const f16_t* Ac = As + s * RM * 1024;
      const f16_t* Bc = Bs + s * RN * 1024;
      f16x8 af[RM], bf[RN];
#pragma unroll
      for (int i = 0; i < RM; ++i)
        af[i] = *(const f16x8*)(Ac + (wr + i * 16 + l16) * 32 + sw);
#pragma unroll
      for (int j = 0; j < RN; ++j)
        bf[j] = *(const f16x8*)(Bc + (wc + j * 16 + l16) * 32 + sw);
#pragma unroll
      for (int i = 0; i < RM; ++i)
#pragma unroll
        for (int j = 0; j < RN; ++j)
          acc[i][j] = mfma16(af[i], bf[j], acc[i][j]);
    }

    __syncthreads();
    Ag += NS * 32; Bg += NS * 32;
  }
}

// ---------------------------------------------------------------------------
// 0) fp32 -> fp16 for x, W1, W2 in one launch. Grid 5120 x 256 x 8 elems.
__global__ __launch_bounds__(256) void cvt_kernel(
    const float* __restrict__ x, const float* __restrict__ W1,
    const float* __restrict__ W2, f16_t* __restrict__ xh,
    f16_t* __restrict__ W1h, f16_t* __restrict__ W2h)
{
  const size_t XN = (size_t)8192 * 1024;
  const size_t WN = (size_t)1024 * 1024;
  size_t i = ((size_t)blockIdx.x * 256 + threadIdx.x) * 8;
  const float* in; f16_t* out;
  if (i < XN)            { in = x;  out = xh; }
  else if (i < XN + WN)  { in = W1; out = W1h; i -= XN; }
  else                   { in = W2; out = W2h; i -= XN + WN; }
  f32x4 a = *(const f32x4*)(in + i);
  f32x4 b = *(const f32x4*)(in + i + 4);
  f16x8 o;
#pragma unroll
  for (int k = 0; k < 4; ++k) { o[k] = (f16_t)a[k]; o[k + 4] = (f16_t)b[k]; }
  *(f16x8*)(out + i) = o;
}

// ---------------------------------------------------------------------------
// 1) fused projection, 128x64 tiles (RM=4, RN=2), BK=64 (r12-exact):
//    Q = xW1^T+b1, V = xW2^T+b2, Vt via pitch-136 LDS transpose epilogue.
//    Grid 64x16=1024 (4 blocks/CU).
__global__ __launch_bounds__(256) void proj_qv_kernel(
    const f16_t* __restrict__ X, const f16_t* __restrict__ W1,
    const f16_t* __restrict__ W2, const float* __restrict__ b1,
    const float* __restrict__ b2, f16_t* __restrict__ Q,
    f16_t* __restrict__ V, f16_t* __restrict__ Vt)
{
  __shared__ __align__(16) f16_t smem[16384];   // 32 KB arena
  f16_t* Xs  = smem;                            // 2 x 128x32 = 8192 f16
  f16_t* W1s = smem + 8192;                     // 2 x  64x32 = 4096 f16
  f16_t* W2s = smem + 12288;                    // 2 x  64x32 = 4096 f16
  constexpr int XSZ = 128 * 32;
  constexpr int WSZ = 64 * 32;

  const int m0 = blockIdx.x * 128;
  const int n0 = blockIdx.y * 64;

  const int tid  = threadIdx.x;
  const int lane = tid & 63;
  const int w    = tid >> 6;
  const int wr   = (w >> 1) * 64;
  const int wc   = (w & 1) * 32;
  const int quad = lane >> 4;
  const int l16  = lane & 15;
  const int sw   = (quad ^ ((l16 >> 1) & 3)) * 8;
  const int r0   = tid >> 2;
  const int kc0  = ((tid & 3) ^ ((r0 >> 1) & 3)) * 8;

  const f16_t* Xg = X + (size_t)(m0 + r0) * 1024 + kc0;
  const f16_t* G1 = W1 + (size_t)(n0 + r0) * 1024 + kc0;
  const f16_t* G2 = W2 + (size_t)(n0 + r0) * 1024 + kc0;

  f32x4 accQ[4][2] = {};
  f32x4 accV[4][2] = {};

  for (int kt = 0; kt < 16; ++kt) {
#pragma unroll
    for (int s = 0; s < 2; ++s) {
      const int ko = s * 32;
      async_copy16(Xg + ko, Xs + s * XSZ + tid * 8);
      async_copy16(Xg + ko + (size_t)64 * 1024, Xs + s * XSZ + (tid + 256) * 8);
      async_copy16(G1 + ko, W1s + s * WSZ + tid * 8);
      async_copy16(G2 + ko, W2s + s * WSZ + tid * 8);
    }
    __syncthreads();

#pragma unroll
    for (int s = 0; s < 2; ++s) {
      f16x8 xf[4], w1f[2], w2f[2];
#pragma unroll
      for (int i = 0; i < 4; ++i)
        xf[i]  = *(const f16x8*)(Xs  + s * XSZ + (wr + i * 16 + l16) * 32 + sw);
#pragma unroll
      for (int j = 0; j < 2; ++j) {
        w1f[j] = *(const f16x8*)(W1s + s * WSZ + (wc + j * 16 + l16) * 32 + sw);
        w2f[j] = *(const f16x8*)(W2s + s * WSZ + (wc + j * 16 + l16) * 32 + sw);
      }
#pragma unroll
      for (int i = 0; i < 4; ++i)
#pragma unroll
        for (int j = 0; j < 2; ++j) {
          accQ[i][j] = mfma16(xf[i], w1f[j], accQ[i][j]);
          accV[i][j] = mfma16(xf[i], w2f[j], accV[i][j]);
        }
    }
    __syncthreads();
    Xg += 64; G1 += 64; G2 += 64;
  }

  f16_t* Ts = smem;
#pragma unroll
  for (int j = 0; j < 2; ++j) {
    const int c   = wc + j * 16 + l16;
    const int col = n0 + c;
    const float bq = b1[col], bv = b2[col];
#pragma unroll
    for (int i = 0; i < 4; ++i)
#pragma unroll
      for (int r = 0; r < 4; ++r) {
        const int k   = wr + i * 16 + quad * 4 + r;
        const int row = m0 + k;
        const float q = accQ[i][j][r] + bq;
        const float v = accV[i][j][r] + bv;
        Q[(size_t)row * 1024 + col] = (f16_t)q;
        V[(size_t)row * 1024 + col] = (f16_t)v;
        Ts[c * 136 + k] = (f16_t)v;
      }
  }
  __syncthreads();

  const size_t vtbase = ((size_t)(m0 >> 11) << 21) + (size_t)n0 * 2048 + (m0 & 2047);
#pragma unroll
  for (int rep = 0; rep < 4; ++rep) {
    const int d  = rep * 16 + (tid >> 4);
    const int c4 = tid & 15;
    f16x8 vv = *(const f16x8*)(Ts + d * 136 + c4 * 8);
    *(f16x8*)(Vt + vtbase + (size_t)d * 2048 + c4 * 8) = vv;
  }
}

// ---------------------------------------------------------------------------
// 2) scores: S[b][q][k] = Q[b,q,:] . V[b,k,:], written FP16. 128x128 tile,
//    BK=64, LDS 32 KB, grid 16x16x4 = 1024 (4 blocks/CU), 16 barrier pairs.
__global__ __launch_bounds__(256) void score_kernel(
    const f16_t* __restrict__ Q, const f16_t* __restrict__ V,
    f16_t* __restrict__ S)
{
  __shared__ __align__(16) f16_t As[2 * 128 * 32];   // 16 KB
  __shared__ __align__(16) f16_t Bs[2 * 128 * 32];   // 16 KB
  const int m0 = blockIdx.x * 128;
  const int n0 = blockIdx.y * 128;
  const size_t boff = (size_t)blockIdx.z * 2048 * 1024;

  f32x4 acc[4][4] = {};
  gemm_core<4, 4, 2>(Q + boff + (size_t)m0 * 1024,
                     V + boff + (size_t)n0 * 1024,
                     1024, 1024, 1024 / 64, As, Bs, acc);

  f16_t* Sb = S + (size_t)blockIdx.z * 2048 * 2048;
  const int lane = threadIdx.x & 63;
  const int w    = threadIdx.x >> 6;
  const int wr   = (w >> 1) * 64, wc = (w & 1) * 64;
  const int quad = lane >> 4,     l16 = lane & 15;

#pragma unroll
  for (int i = 0; i < 4; ++i)
#pragma unroll
    for (int j = 0; j < 4; ++j)
#pragma unroll
      for (int r = 0; r < 4; ++r) {
        const int row = m0 + wr + i * 16 + quad * 4 + r;
        const int col = n0 + wc + j * 16 + l16;
        Sb[(size_t)row * 2048 + col] = (f16_t)acc[i][j][r];
      }
}

// ---------------------------------------------------------------------------
// 3) softmax: one row per HALF-WAVE. 8 rows/block, grid 1024. No LDS, no
//    barriers: shfl_xor(16..1) reductions stay within the 32-lane half.
//    Two passes over 8 f16x8 chunks held in registers.
__global__ __launch_bounds__(256) void softmax_kernel(f16_t* __restrict__ S)
{
  const int tid    = threadIdx.x;
  const int lane32 = tid & 31;
  const int rowid  = blockIdx.x * 8 + (tid >> 5);
  f16_t* row = S + (size_t)rowid * 2048;

  f16x8 v[8];
#pragma unroll
  for (int c = 0; c < 8; ++c)
    v[c] = *(const f16x8*)(row + c * 256 + lane32 * 8);

  // pass 1: row max
  float m = -3.0e38f;
#pragma unroll
  for (int c = 0; c < 8; ++c)
#pragma unroll
    for (int k = 0; k < 8; ++k) m = fmaxf(m, (float)v[c][k]);
#pragma unroll
  for (int off = 16; off >= 1; off >>= 1) m = fmaxf(m, __shfl_xor(m, off));

  // pass 2: exp & sum
  float s = 0.f;
  float e[8][8];
#pragma unroll
  for (int c = 0; c < 8; ++c)
#pragma unroll
    for (int k = 0; k < 8; ++k) {
      e[c][k] = __expf((float)v[c][k] - m);
      s += e[c][k];
    }
#pragma unroll
  for (int off = 16; off >= 1; off >>= 1) s += __shfl_xor(s, off);
  const float inv = 1.f / s;

#pragma unroll
  for (int c = 0; c < 8; ++c) {
    f16x8 o;
#pragma unroll
    for (int k = 0; k < 8; ++k) o[k] = (f16_t)(e[c][k] * inv);
    *(f16x8*)(row + c * 256 + lane32 * 8) = o;
  }
}

// ---------------------------------------------------------------------------
// 4) out[b][q][d] = sum_k P[b][q][k] * Vt[b][d][k] -> fp32. P pitch 2048 f16.
//    128x128 tile, BK=64, LDS 32 KB, grid 16x8x4 = 512 (2 blocks/CU).
__global__ __launch_bounds__(256) void out_kernel(
    const f16_t* __restrict__ P, const f16_t* __restrict__ Vt,
    float* __restrict__ Out)
{
  __shared__ __align__(16) f16_t As[2 * 128 * 32];   // 16 KB
  __shared__ __align__(16) f16_t Bs[2 * 128 * 32];   // 16 KB
  const int m0 = blockIdx.x * 128;
  const int n0 = blockIdx.y * 128;
  const size_t poff  = (size_t)blockIdx.z * 2048 * 2048;
  const size_t vtoff = (size_t)blockIdx.z * 1024 * 2048;

  f32x4 acc[4][4] = {};
  gemm_core<4, 4, 2>(P + poff + (size_t)m0 * 2048,
                     Vt + vtoff + (size_t)n0 * 2048,
                     2048, 2048, 2048 / 64, As, Bs, acc);

  float* Ob = Out + (size_t)blockIdx.z * 2048 * 1024;
  const int lane = threadIdx.x & 63;
  const int w    = threadIdx.x >> 6;
  const int wr   = (w >> 1) * 64, wc = (w & 1) * 64;
  const int quad = lane >> 4,     l16 = lane & 15;

#pragma unroll
  for (int i = 0; i < 4; ++i)
#pragma unroll
    for (int j = 0; j < 4; ++j)
#pragma unroll
      for (int r = 0; r < 4; ++r) {
        const int row = m0 + wr + i * 16 + quad * 4 + r;
        const int col = n0 + wc + j * 16 + l16;
        Ob[(size_t)row * 1024 + col] = acc[i][j][r];
      }
}

// ---------------------------------------------------------------------------
extern "C" void kernel_launch(void* const* d_in, const int* in_sizes, int n_in,
                              void* d_out, int out_size, void* d_ws, size_t ws_size,
                              hipStream_t stream) {
  const float* x  = (const float*)d_in[0];
  const float* W1 = (const float*)d_in[1];
  const float* b1 = (const float*)d_in[2];
  const float* W2 = (const float*)d_in[3];
  const float* b2 = (const float*)d_in[4];
  float* out = (float*)d_out;

  const size_t QN = (size_t)8192 * 1024;
  const size_t WN = (size_t)1024 * 1024;
  f16_t* xh  = (f16_t*)d_ws;       // 16 MiB
  f16_t* W1h = xh + QN;            //  2 MiB
  f16_t* W2h = W1h + WN;           //  2 MiB
  f16_t* Q   = W2h + WN;           // 16 MiB
  f16_t* V   = Q + QN;             // 16 MiB
  f16_t* Vt  = V + QN;             // 16 MiB [4][1024][2048]
  f16_t* S   = Vt + QN;            // 32 MiB fp16 [4][2048][2048], P in-place

  dim3 blk(256);
  cvt_kernel<<<5120, blk, 0, stream>>>(x, W1, W2, xh, W1h, W2h);
  proj_qv_kernel<<<dim3(64, 16), blk, 0, stream>>>(xh, W1h, W2h, b1, b2, Q, V, Vt);
  score_kernel<<<dim3(16, 16, 4), blk, 0, stream>>>(Q, V, S);
  softmax_kernel<<<1024, blk, 0, stream>>>(S);
  out_kernel<<<dim3(16, 8, 4), blk, 0, stream>>>(S, Vt, out);
}